// Round 2
// baseline (738.582 us; speedup 1.0000x reference)
//
#include <hip/hip_runtime.h>

typedef _Float16 half8 __attribute__((ext_vector_type(8)));
typedef _Float16 half2v __attribute__((ext_vector_type(2)));
typedef float f32x4 __attribute__((ext_vector_type(4)));

#define S_LEN 4096
#define D_DIM 4096
#define HD 128

// ws layout (6 MiB total -- keep small, ws_size is not guaranteed large):
//   qw [2][4096][128] f16 @ 0       (2 MiB)
//   kw [2][4096][128] f16 @ 2 MiB   (2 MiB)
//   vt [2][128][4096] f16 @ 4 MiB   (2 MiB)

// ---------------- kernel 1: QKV projection GEMM (f16 MFMA) + fused RoPE ----------------
// C[m][n] = sum_k x[m][k] * W[n][k]; grid (3 proj, 64 m-tiles), 128x128 tile, BK=32.
// W is converted fp32->f16 during LDS staging (no separate weight-convert kernel).
// bx==2 (V) writes its output directly transposed into vt (2B scattered stores, 2 MiB).
__global__ __launch_bounds__(256) void proj_kernel(const float* __restrict__ x,
                                                   const float* __restrict__ wq,
                                                   const float* __restrict__ wk,
                                                   const float* __restrict__ wv,
                                                   _Float16* __restrict__ qw,
                                                   _Float16* __restrict__ kw,
                                                   _Float16* __restrict__ vt) {
    __shared__ __align__(16) _Float16 Ash[128 * 32];
    __shared__ __align__(16) _Float16 Bsh[128 * 32];
    const int tid = threadIdx.x;
    const int bx = blockIdx.x;            // 0=q, 1=k, 2=v (tile width 128 == head dim)
    const int M0 = blockIdx.y * 128;
    const float* w = (bx == 0) ? wq : (bx == 1) ? wk : wv;
    const int lane = tid & 63, wid = tid >> 6;
    const int wr = wid >> 1, wc = wid & 1;
    const int l15 = lane & 15, quad = lane >> 4;

    // staging: thread -> (row, 16-col half); 256 threads cover 128x32 for A and B
    const int srow = tid >> 1;
    const int shalf = (tid & 1) * 16;
    const float* xsrc = x + (size_t)(M0 + srow) * D_DIM + shalf;
    const float* wsrc = w + (size_t)srow * D_DIM + shalf;
    _Float16* ash = &Ash[srow * 32 + shalf];
    _Float16* bsh = &Bsh[srow * 32 + shalf];

    f32x4 acc[4][4];
    for (int mi = 0; mi < 4; ++mi)
        for (int ni = 0; ni < 4; ++ni)
            acc[mi][ni] = (f32x4){0.f, 0.f, 0.f, 0.f};

    for (int k0 = 0; k0 < D_DIM; k0 += 32) {
        float4 a0 = *(const float4*)(xsrc + k0);
        float4 a1 = *(const float4*)(xsrc + k0 + 4);
        float4 a2 = *(const float4*)(xsrc + k0 + 8);
        float4 a3 = *(const float4*)(xsrc + k0 + 12);
        float4 b0 = *(const float4*)(wsrc + k0);
        float4 b1 = *(const float4*)(wsrc + k0 + 4);
        float4 b2 = *(const float4*)(wsrc + k0 + 8);
        float4 b3 = *(const float4*)(wsrc + k0 + 12);
        half8 ha0 = { (_Float16)a0.x, (_Float16)a0.y, (_Float16)a0.z, (_Float16)a0.w,
                      (_Float16)a1.x, (_Float16)a1.y, (_Float16)a1.z, (_Float16)a1.w };
        half8 ha1 = { (_Float16)a2.x, (_Float16)a2.y, (_Float16)a2.z, (_Float16)a2.w,
                      (_Float16)a3.x, (_Float16)a3.y, (_Float16)a3.z, (_Float16)a3.w };
        half8 hb0 = { (_Float16)b0.x, (_Float16)b0.y, (_Float16)b0.z, (_Float16)b0.w,
                      (_Float16)b1.x, (_Float16)b1.y, (_Float16)b1.z, (_Float16)b1.w };
        half8 hb1 = { (_Float16)b2.x, (_Float16)b2.y, (_Float16)b2.z, (_Float16)b2.w,
                      (_Float16)b3.x, (_Float16)b3.y, (_Float16)b3.z, (_Float16)b3.w };
        *(half8*)ash = ha0;
        *(half8*)(ash + 8) = ha1;
        *(half8*)bsh = hb0;
        *(half8*)(bsh + 8) = hb1;
        __syncthreads();
        half8 af[4], bf[4];
        for (int mi = 0; mi < 4; ++mi)
            af[mi] = *(const half8*)&Ash[(wr * 64 + mi * 16 + l15) * 32 + quad * 8];
        for (int ni = 0; ni < 4; ++ni)
            bf[ni] = *(const half8*)&Bsh[(wc * 64 + ni * 16 + l15) * 32 + quad * 8];
        for (int mi = 0; mi < 4; ++mi)
            for (int ni = 0; ni < 4; ++ni)
                acc[mi][ni] = __builtin_amdgcn_mfma_f32_16x16x32_f16(af[mi], bf[ni],
                                                                     acc[mi][ni], 0, 0, 0);
        __syncthreads();
    }

    // epilogue: RoPE for q/k -> [m][hd]; V written directly transposed -> vt[b][hd][s]
    _Float16* dst = (bx == 0) ? qw : kw;
    for (int mi = 0; mi < 4; ++mi) {
        for (int ni = 0; ni < 4; ++ni) {
            f32x4 c = acc[mi][ni];
            const int hd = wc * 64 + ni * 16 + l15;                    // 0..127
            // theta_p = 10000^(-p/32) = 2^(-p * log2(10000)/32), p = hd>>1
            const float theta = exp2f((float)(hd >> 1) * -0.4152410118609203f);
            for (int r = 0; r < 4; ++r) {
                const int m = M0 + wr * 64 + mi * 16 + quad * 4 + r;   // global row (b*S + s)
                const int s = m & (S_LEN - 1);
                float v = c[r];
                if (bx < 2) {
                    float sn, cn;
                    sincosf((float)s * theta, &sn, &cn);
                    float vp = __shfl_xor(v, 1);
                    v = (l15 & 1) ? fmaf(v, cn, vp * sn) : fmaf(v, cn, -vp * sn);
                    dst[(size_t)m * HD + hd] = (_Float16)v;
                } else {
                    vt[((size_t)(m >> 12) * HD + hd) * S_LEN + s] = (_Float16)v;
                }
            }
        }
    }
}

// ---------------- kernel 2: causal flash attention, S^T/O^T formulation ----------------
// S^T = K Q^T via mfma(A=K-frag, B=Q-frag): C col = lane&15 = q, row = quad*4+r = key.
// Per-lane softmax state (each lane owns one q-row) -> 4 shuffles per 32-key tile.
// P^T re-layout to PV B-operand via 8 ds_bpermute on packed f16 (no LDS, no barriers).
// O^T = Vt P^T via mfma(A=Vt-frag, B=P-frag): row = d, col = q.
template<bool MASKED>
__device__ __forceinline__ void attn_tile(int kbase, int qg, int l15, int quad,
                                          const _Float16* __restrict__ kb,
                                          const _Float16* __restrict__ vtb,
                                          const half8* bq, f32x4* acc,
                                          float& mrun, float& lrun) {
    const float csc = 0.1275174348796053f;  // (1/sqrt(128)) * log2(e)
    // K A-frags: two 16-key halves
    const _Float16* kr = kb + (size_t)(kbase + l15) * HD + quad * 8;
    f32x4 st0 = (f32x4){0.f, 0.f, 0.f, 0.f};
    f32x4 st1 = (f32x4){0.f, 0.f, 0.f, 0.f};
    for (int kk = 0; kk < 4; ++kk) {
        half8 k0 = *(const half8*)(kr + kk * 32);
        half8 k1 = *(const half8*)(kr + 16 * HD + kk * 32);
        st0 = __builtin_amdgcn_mfma_f32_16x16x32_f16(k0, bq[kk], st0, 0, 0, 0);
        st1 = __builtin_amdgcn_mfma_f32_16x16x32_f16(k1, bq[kk], st1, 0, 0, 0);
    }
    // prefetch V^T B... A-frags for PV (independent of softmax)
    half8 va[8];
    const _Float16* vr = vtb + (size_t)l15 * S_LEN + kbase + quad * 8;
    for (int c = 0; c < 8; ++c)
        va[c] = *(const half8*)(vr + (size_t)c * 16 * S_LEN);
    // scale (+mask) in log2 domain
    float p0[4], p1[4];
    float mloc = -1e30f;
    for (int r = 0; r < 4; ++r) {
        float v0 = st0[r] * csc;
        float v1 = st1[r] * csc;
        if (MASKED) {
            const int key0 = kbase + quad * 4 + r;
            if (key0 > qg)      v0 = -1e30f;
            if (key0 + 16 > qg) v1 = -1e30f;
        }
        p0[r] = v0; p1[r] = v1;
        mloc = fmaxf(mloc, fmaxf(v0, v1));
    }
    mloc = fmaxf(mloc, __shfl_xor(mloc, 16));
    mloc = fmaxf(mloc, __shfl_xor(mloc, 32));
    const float mnew = fmaxf(mrun, mloc);
    const float alpha = exp2f(mrun - mnew);
    mrun = mnew;
    float ls = 0.f;
    for (int r = 0; r < 4; ++r) {
        p0[r] = exp2f(p0[r] - mnew);
        p1[r] = exp2f(p1[r] - mnew);
        ls += p0[r] + p1[r];
    }
    ls += __shfl_xor(ls, 16);
    ls += __shfl_xor(ls, 32);
    lrun = lrun * alpha + ls;
    for (int c = 0; c < 8; ++c)
        acc[c] *= alpha;
    // pack P to f16 pairs, then cross-quad gather: dest (q=l15, quad) needs keys quad*8..+7
    int ph0 = __builtin_bit_cast(int, __builtin_amdgcn_cvt_pkrtz(p0[0], p0[1]));
    int ph1 = __builtin_bit_cast(int, __builtin_amdgcn_cvt_pkrtz(p0[2], p0[3]));
    int ph2 = __builtin_bit_cast(int, __builtin_amdgcn_cvt_pkrtz(p1[0], p1[1]));
    int ph3 = __builtin_bit_cast(int, __builtin_amdgcn_cvt_pkrtz(p1[2], p1[3]));
    const int s0 = (l15 + (((quad << 1)    ) & 3) * 16) * 4;
    const int s1 = (l15 + (((quad << 1) + 1) & 3) * 16) * 4;
    int a0 = __builtin_amdgcn_ds_bpermute(s0, ph0);
    int a1 = __builtin_amdgcn_ds_bpermute(s0, ph1);
    int a2 = __builtin_amdgcn_ds_bpermute(s1, ph0);
    int a3 = __builtin_amdgcn_ds_bpermute(s1, ph1);
    int b0 = __builtin_amdgcn_ds_bpermute(s0, ph2);
    int b1 = __builtin_amdgcn_ds_bpermute(s0, ph3);
    int b2 = __builtin_amdgcn_ds_bpermute(s1, ph2);
    int b3 = __builtin_amdgcn_ds_bpermute(s1, ph3);
    const bool lo = quad < 2;  // quads 0,1 consume keys 0..15 (frag0), quads 2,3 keys 16..31
    int4 pi = { lo ? a0 : b0, lo ? a1 : b1, lo ? a2 : b2, lo ? a3 : b3 };
    half8 pf = __builtin_bit_cast(half8, pi);
    for (int c = 0; c < 8; ++c)
        acc[c] = __builtin_amdgcn_mfma_f32_16x16x32_f16(va[c], pf, acc[c], 0, 0, 0);
}

__global__ __launch_bounds__(64) void attn_kernel(const _Float16* __restrict__ q,
                                                  const _Float16* __restrict__ k,
                                                  const _Float16* __restrict__ vt,
                                                  float* __restrict__ out) {
    const int lane = threadIdx.x;
    const int l15 = lane & 15, quad = lane >> 4;
    const int bidx = blockIdx.x;
    const int b = bidx & 1;
    const int t = 255 - (bidx >> 1);  // longest q-tiles dispatched first
    const int qb = t * 16;
    const int qg = qb + l15;          // this lane's q row

    // Q as B-operand fragments (lane = q row)
    const _Float16* qp = q + (size_t)(b * S_LEN + qb) * HD;
    half8 bq[4];
    for (int kk = 0; kk < 4; ++kk)
        bq[kk] = *(const half8*)&qp[l15 * HD + kk * 32 + quad * 8];

    f32x4 acc[8];
    for (int c = 0; c < 8; ++c) acc[c] = (f32x4){0.f, 0.f, 0.f, 0.f};
    float mrun = -1e30f, lrun = 0.f;

    const _Float16* kb = k + (size_t)b * S_LEN * HD;
    const _Float16* vtb = vt + (size_t)b * HD * S_LEN;

    const int nfull = (qb + 1) >> 5;  // unmasked 32-key tiles; exactly one masked tile follows
    for (int kt = 0; kt < nfull; ++kt)
        attn_tile<false>(kt * 32, qg, l15, quad, kb, vtb, bq, acc, mrun, lrun);
    attn_tile<true>(nfull * 32, qg, l15, quad, kb, vtb, bq, acc, mrun, lrun);

    // epilogue: O^T frag -> out[q][d]; row q = lane, cols d contiguous per reg quartet
    const float inv = 1.0f / lrun;
    float* ob = out + (size_t)(b * S_LEN + qg) * HD;
    for (int c = 0; c < 8; ++c) {
        f32x4 o = acc[c] * inv;
        *(float4*)&ob[c * 16 + quad * 4] = (float4){o[0], o[1], o[2], o[3]};
    }
}

extern "C" void kernel_launch(void* const* d_in, const int* in_sizes, int n_in,
                              void* d_out, int out_size, void* d_ws, size_t ws_size,
                              hipStream_t stream) {
    const float* x  = (const float*)d_in[0];
    const float* Wq = (const float*)d_in[1];
    const float* Wk = (const float*)d_in[2];
    const float* Wv = (const float*)d_in[3];
    float* out = (float*)d_out;
    char* ws = (char*)d_ws;
    _Float16* qw = (_Float16*)(ws);
    _Float16* kw = (_Float16*)(ws + (2u << 20));
    _Float16* vt = (_Float16*)(ws + (4u << 20));

    proj_kernel<<<dim3(3, 64), dim3(256), 0, stream>>>(x, Wq, Wk, Wv, qw, kw, vt);
    attn_kernel<<<dim3(512), dim3(64), 0, stream>>>(qw, kw, vt, out);
}

// Round 3
// 374.006 us; speedup vs baseline: 1.9748x; 1.9748x over previous
//
#include <hip/hip_runtime.h>

typedef _Float16 half8 __attribute__((ext_vector_type(8)));
typedef float f32x4 __attribute__((ext_vector_type(4)));

#define S_LEN 4096
#define D_DIM 4096
#define HD 128

// ws layout (6 MiB): qw [8192][128] f16 @0; kw @2MiB; vt [2][128][4096] f16 @4MiB

// ---------------- kernel 1: QKV projection + fused RoPE ----------------
// grid (3, 128): bx = projection, by = 64-row m-tile. block 256 = 4 waves.
// Wave w computes rows [16w,16w+16) x 128 cols. BK=32, register prefetch.
// Epilogue goes through LDS so all global stores are 16B/lane coalesced.
#define ASTR 40   // A LDS row stride (f16): 80B, 16B-aligned, 2-way banks
#define BSTR 40
#define QSTR 136  // q/k epilogue [64][136]: 272B rows
#define VSTR 72   // vt epilogue [128][72]: 144B rows
__global__ __launch_bounds__(256) void proj_kernel(const float* __restrict__ x,
                                                   const float* __restrict__ wq,
                                                   const float* __restrict__ wk,
                                                   const float* __restrict__ wv,
                                                   _Float16* __restrict__ qw,
                                                   _Float16* __restrict__ kw,
                                                   _Float16* __restrict__ vt) {
    __shared__ __align__(16) _Float16 smem[128 * VSTR];  // 18 KiB, union staging/epilogue
    _Float16* Ash = smem;                 // [64][ASTR]
    _Float16* Bsh = smem + 64 * ASTR;     // [128][BSTR]
    const int tid = threadIdx.x;
    const int bx = blockIdx.x;
    const int M0 = blockIdx.y * 64;       // global row (b*S + s)
    const float* w = (bx == 0) ? wq : (bx == 1) ? wk : wv;
    const int lane = tid & 63, wv_ = tid >> 6;
    const int l15 = lane & 15, quad = lane >> 4;

    // staging: A 64x32 f32 (2 float4/thread), B 128x32 f32 (4 float4/thread)
    const int arow = tid >> 2, acol = (tid & 3) * 8;
    const int brow = tid >> 1, bcol = (tid & 1) * 16;
    const float* xa = x + (size_t)(M0 + arow) * D_DIM + acol;
    const float* wb = w + (size_t)brow * D_DIM + bcol;
    _Float16* ash = &Ash[arow * ASTR + acol];
    _Float16* bsh = &Bsh[brow * BSTR + bcol];

    f32x4 acc[8];
    for (int ni = 0; ni < 8; ++ni) acc[ni] = (f32x4){0.f, 0.f, 0.f, 0.f};

    float4 a0 = *(const float4*)(xa);
    float4 a1 = *(const float4*)(xa + 4);
    float4 b0 = *(const float4*)(wb);
    float4 b1 = *(const float4*)(wb + 4);
    float4 b2 = *(const float4*)(wb + 8);
    float4 b3 = *(const float4*)(wb + 12);

    for (int k0 = 0; k0 < D_DIM; k0 += 32) {
        half8 ha = { (_Float16)a0.x, (_Float16)a0.y, (_Float16)a0.z, (_Float16)a0.w,
                     (_Float16)a1.x, (_Float16)a1.y, (_Float16)a1.z, (_Float16)a1.w };
        half8 hb0 = { (_Float16)b0.x, (_Float16)b0.y, (_Float16)b0.z, (_Float16)b0.w,
                      (_Float16)b1.x, (_Float16)b1.y, (_Float16)b1.z, (_Float16)b1.w };
        half8 hb1 = { (_Float16)b2.x, (_Float16)b2.y, (_Float16)b2.z, (_Float16)b2.w,
                      (_Float16)b3.x, (_Float16)b3.y, (_Float16)b3.z, (_Float16)b3.w };
        *(half8*)ash = ha;
        *(half8*)bsh = hb0;
        *(half8*)(bsh + 8) = hb1;
        __syncthreads();
        if (k0 + 32 < D_DIM) {  // prefetch next slab; latency hidden under MFMA phase
            a0 = *(const float4*)(xa + k0 + 32);
            a1 = *(const float4*)(xa + k0 + 36);
            b0 = *(const float4*)(wb + k0 + 32);
            b1 = *(const float4*)(wb + k0 + 36);
            b2 = *(const float4*)(wb + k0 + 40);
            b3 = *(const float4*)(wb + k0 + 44);
        }
        half8 af = *(const half8*)&Ash[(wv_ * 16 + l15) * ASTR + quad * 8];
        half8 bf[8];
        for (int ni = 0; ni < 8; ++ni)
            bf[ni] = *(const half8*)&Bsh[(ni * 16 + l15) * BSTR + quad * 8];
        for (int ni = 0; ni < 8; ++ni)
            acc[ni] = __builtin_amdgcn_mfma_f32_16x16x32_f16(af, bf[ni], acc[ni], 0, 0, 0);
        __syncthreads();
    }

    // ---- epilogue via LDS: C row = wv_*16+quad*4+r, col = ni*16+l15 ----
    if (bx < 2) {
        // RoPE, then Csh[row][col] then coalesced store
        for (int ni = 0; ni < 8; ++ni) {
            const int hd = ni * 16 + l15;
            const float theta = exp2f((float)(hd >> 1) * -0.4152410118609203f);
            for (int r = 0; r < 4; ++r) {
                const int row = wv_ * 16 + quad * 4 + r;
                const int s = (M0 + row) & (S_LEN - 1);
                float v = acc[ni][r];
                float sn, cn;
                sincosf((float)s * theta, &sn, &cn);
                float vp = __shfl_xor(v, 1);
                v = (l15 & 1) ? fmaf(v, cn, vp * sn) : fmaf(v, cn, -vp * sn);
                smem[row * QSTR + hd] = (_Float16)v;
            }
        }
        __syncthreads();
        _Float16* dst = ((bx == 0) ? qw : kw) + (size_t)M0 * HD;
        const int row = tid >> 2, c0 = (tid & 3) * 32;
        for (int j = 0; j < 4; ++j) {
            half8 v = *(const half8*)&smem[row * QSTR + c0 + j * 8];
            *(half8*)&dst[row * HD + c0 + j * 8] = v;
        }
    } else {
        // V: transpose in LDS -> vt[b][hd][s], coalesced 16B stores along s
        for (int ni = 0; ni < 8; ++ni) {
            const int hd = ni * 16 + l15;
            for (int r = 0; r < 4; ++r) {
                const int row = wv_ * 16 + quad * 4 + r;
                smem[hd * VSTR + row] = (_Float16)acc[ni][r];
            }
        }
        __syncthreads();
        _Float16* dst = vt + ((size_t)(M0 >> 12) * HD) * S_LEN + (M0 & (S_LEN - 1));
        const int hd = tid >> 1, s0 = (tid & 1) * 32;
        for (int j = 0; j < 4; ++j) {
            half8 v = *(const half8*)&smem[hd * VSTR + s0 + j * 8];
            *(half8*)&dst[(size_t)hd * S_LEN + s0 + j * 8] = v;
        }
    }
}

// ---------------- kernel 2: causal flash attention, S^T/O^T, key-split x4 ----------------
template<bool MASKED>
__device__ __forceinline__ void attn_tile(int kbase, int qg, int l15, int quad,
                                          const _Float16* __restrict__ kb,
                                          const _Float16* __restrict__ vtb,
                                          const half8* bq, f32x4* acc,
                                          float& mrun, float& lrun) {
    const float csc = 0.1275174348796053f;  // (1/sqrt(128)) * log2(e)
    const _Float16* kr = kb + (size_t)(kbase + l15) * HD + quad * 8;
    f32x4 st0 = (f32x4){0.f, 0.f, 0.f, 0.f};
    f32x4 st1 = (f32x4){0.f, 0.f, 0.f, 0.f};
    for (int kk = 0; kk < 4; ++kk) {
        half8 k0 = *(const half8*)(kr + kk * 32);
        half8 k1 = *(const half8*)(kr + 16 * HD + kk * 32);
        st0 = __builtin_amdgcn_mfma_f32_16x16x32_f16(k0, bq[kk], st0, 0, 0, 0);
        st1 = __builtin_amdgcn_mfma_f32_16x16x32_f16(k1, bq[kk], st1, 0, 0, 0);
    }
    half8 va[8];
    const _Float16* vr = vtb + (size_t)l15 * S_LEN + kbase + quad * 8;
    for (int c = 0; c < 8; ++c)
        va[c] = *(const half8*)(vr + (size_t)c * 16 * S_LEN);
    float p0[4], p1[4];
    float mloc = -1e30f;
    for (int r = 0; r < 4; ++r) {
        float v0 = st0[r] * csc;
        float v1 = st1[r] * csc;
        if (MASKED) {
            const int key0 = kbase + quad * 4 + r;
            if (key0 > qg)      v0 = -1e30f;
            if (key0 + 16 > qg) v1 = -1e30f;
        }
        p0[r] = v0; p1[r] = v1;
        mloc = fmaxf(mloc, fmaxf(v0, v1));
    }
    mloc = fmaxf(mloc, __shfl_xor(mloc, 16));
    mloc = fmaxf(mloc, __shfl_xor(mloc, 32));
    const float mnew = fmaxf(mrun, mloc);
    const float alpha = exp2f(mrun - mnew);
    mrun = mnew;
    float ls = 0.f;
    for (int r = 0; r < 4; ++r) {
        p0[r] = exp2f(p0[r] - mnew);
        p1[r] = exp2f(p1[r] - mnew);
        ls += p0[r] + p1[r];
    }
    ls += __shfl_xor(ls, 16);
    ls += __shfl_xor(ls, 32);
    lrun = lrun * alpha + ls;
    for (int c = 0; c < 8; ++c)
        acc[c] *= alpha;
    int ph0 = __builtin_bit_cast(int, __builtin_amdgcn_cvt_pkrtz(p0[0], p0[1]));
    int ph1 = __builtin_bit_cast(int, __builtin_amdgcn_cvt_pkrtz(p0[2], p0[3]));
    int ph2 = __builtin_bit_cast(int, __builtin_amdgcn_cvt_pkrtz(p1[0], p1[1]));
    int ph3 = __builtin_bit_cast(int, __builtin_amdgcn_cvt_pkrtz(p1[2], p1[3]));
    const int s0 = (l15 + (((quad << 1)    ) & 3) * 16) * 4;
    const int s1 = (l15 + (((quad << 1) + 1) & 3) * 16) * 4;
    int a0 = __builtin_amdgcn_ds_bpermute(s0, ph0);
    int a1 = __builtin_amdgcn_ds_bpermute(s0, ph1);
    int a2 = __builtin_amdgcn_ds_bpermute(s1, ph0);
    int a3 = __builtin_amdgcn_ds_bpermute(s1, ph1);
    int b0 = __builtin_amdgcn_ds_bpermute(s0, ph2);
    int b1 = __builtin_amdgcn_ds_bpermute(s0, ph3);
    int b2 = __builtin_amdgcn_ds_bpermute(s1, ph2);
    int b3 = __builtin_amdgcn_ds_bpermute(s1, ph3);
    const bool lo = quad < 2;
    int4 pi = { lo ? a0 : b0, lo ? a1 : b1, lo ? a2 : b2, lo ? a3 : b3 };
    half8 pf = __builtin_bit_cast(half8, pi);
    for (int c = 0; c < 8; ++c)
        acc[c] = __builtin_amdgcn_mfma_f32_16x16x32_f16(va[c], pf, acc[c], 0, 0, 0);
}

// block 256 = 4 waves; one q-tile (16 rows) per block; waves take key-tiles kt%4==w,
// flash-combine partials (m,l,O) through LDS at the end.
__global__ __launch_bounds__(256) void attn_kernel(const _Float16* __restrict__ q,
                                                   const _Float16* __restrict__ k,
                                                   const _Float16* __restrict__ vt,
                                                   float* __restrict__ out) {
    __shared__ __align__(16) float Osh[4][16][132];
    __shared__ float msh[4][16];
    __shared__ float lsh[4][16];
    const int tid = threadIdx.x;
    const int lane = tid & 63, wv_ = tid >> 6;
    const int l15 = lane & 15, quad = lane >> 4;
    const int bidx = blockIdx.x;
    const int b = bidx & 1;
    const int t = 255 - (bidx >> 1);  // longest q-tiles first
    const int qb = t * 16;
    const int qg = qb + l15;

    const _Float16* qp = q + (size_t)(b * S_LEN + qb) * HD;
    half8 bq[4];
    for (int kk = 0; kk < 4; ++kk)
        bq[kk] = *(const half8*)&qp[l15 * HD + kk * 32 + quad * 8];

    f32x4 acc[8];
    for (int c = 0; c < 8; ++c) acc[c] = (f32x4){0.f, 0.f, 0.f, 0.f};
    float mrun = -1e30f, lrun = 0.f;

    const _Float16* kb = k + (size_t)b * S_LEN * HD;
    const _Float16* vtb = vt + (size_t)b * HD * S_LEN;

    const int nfull = (qb + 1) >> 5;
    for (int kt = wv_; kt < nfull; kt += 4)
        attn_tile<false>(kt * 32, qg, l15, quad, kb, vtb, bq, acc, mrun, lrun);
    if ((nfull & 3) == wv_)
        attn_tile<true>(nfull * 32, qg, l15, quad, kb, vtb, bq, acc, mrun, lrun);

    // per-wave partials -> LDS
    for (int c = 0; c < 8; ++c)
        *(f32x4*)&Osh[wv_][l15][c * 16 + quad * 4] = acc[c];
    if (quad == 0) { msh[wv_][l15] = mrun; lsh[wv_][l15] = lrun; }
    __syncthreads();

    // combine: thread -> (q row, 8-wide d group)
    const int qr = tid >> 4, dg = (tid & 15) * 8;
    float m0 = msh[0][qr], m1 = msh[1][qr], m2 = msh[2][qr], m3 = msh[3][qr];
    float mm = fmaxf(fmaxf(m0, m1), fmaxf(m2, m3));
    float f0 = exp2f(m0 - mm), f1 = exp2f(m1 - mm), f2 = exp2f(m2 - mm), f3 = exp2f(m3 - mm);
    float l = lsh[0][qr] * f0 + lsh[1][qr] * f1 + lsh[2][qr] * f2 + lsh[3][qr] * f3;
    f32x4 oa = (f32x4){0.f, 0.f, 0.f, 0.f}, ob = oa;
    oa += *(f32x4*)&Osh[0][qr][dg] * f0;  ob += *(f32x4*)&Osh[0][qr][dg + 4] * f0;
    oa += *(f32x4*)&Osh[1][qr][dg] * f1;  ob += *(f32x4*)&Osh[1][qr][dg + 4] * f1;
    oa += *(f32x4*)&Osh[2][qr][dg] * f2;  ob += *(f32x4*)&Osh[2][qr][dg + 4] * f2;
    oa += *(f32x4*)&Osh[3][qr][dg] * f3;  ob += *(f32x4*)&Osh[3][qr][dg + 4] * f3;
    const float inv = 1.0f / l;
    float* op = out + (size_t)(b * S_LEN + qb + qr) * HD + dg;
    *(float4*)op       = (float4){oa[0] * inv, oa[1] * inv, oa[2] * inv, oa[3] * inv};
    *(float4*)(op + 4) = (float4){ob[0] * inv, ob[1] * inv, ob[2] * inv, ob[3] * inv};
}

extern "C" void kernel_launch(void* const* d_in, const int* in_sizes, int n_in,
                              void* d_out, int out_size, void* d_ws, size_t ws_size,
                              hipStream_t stream) {
    const float* x  = (const float*)d_in[0];
    const float* Wq = (const float*)d_in[1];
    const float* Wk = (const float*)d_in[2];
    const float* Wv = (const float*)d_in[3];
    float* out = (float*)d_out;
    char* ws = (char*)d_ws;
    _Float16* qw = (_Float16*)(ws);
    _Float16* kw = (_Float16*)(ws + (2u << 20));
    _Float16* vt = (_Float16*)(ws + (4u << 20));

    proj_kernel<<<dim3(3, 128), dim3(256), 0, stream>>>(x, Wq, Wk, Wv, qw, kw, vt);
    attn_kernel<<<dim3(512), dim3(256), 0, stream>>>(qw, kw, vt, out);
}